// Round 1
// baseline (154799.487 us; speedup 1.0000x reference)
//
#include <hip/hip_runtime.h>
#include <math.h>

// ResRnn on MI355X.
// Reformulated in pre-activation space:
//   u_{t} = v_{t-1} @ Wc + bias_t + x_t @ W1p^T,   v_t = g(u_t)
// where g(h) = h + bend*outer*sin(h*inner) (elementwise, per-column coeffs),
//   Wc = W2^T W1^T  (so the read-transposed WT[n][k] = (W1@W2)[n][k]),
//   W1p = W1[:, :256],  bias_0 = b1 + s0@W1^T,  bias_{t>0} = b1 + b2@W1^T.
// Final: stream = v_{2047} @ W2^T + b2;  out = [stream[:, :64], stream].
// One grid barrier per step (2048 total) instead of 2 (4096).

#define WDIM 1024
#define KX 256
#define BATCH 64
#define SEQ_N 2048
#define WSTRIDE 1280   // WT row stride: 1024 (Wc part) + 256 (input-inject part)
#define NB 256         // blocks in cooperative grid

// ---------------- workspace layout (floats) ----------------
// [0, 1310720)          WT   [1024][1280]
// [1310720, 1311744)    b1c  [1024]
// [1311744, 1312768)    c0   [1024]
// [1312768, 1378304)    vA   [64][1024]
// [1378304, 1443840)    vB   [64][1024]
// byte offset 5775360:  unsigned bar[2]  (arrive count, generation)

// ---------------- grid barrier ----------------
__device__ __forceinline__ void gbar(unsigned* bar, unsigned target) {
  __syncthreads();
  if (threadIdx.x == 0) {
    __threadfence();  // release this block's prior global writes (agent scope)
    unsigned old = __hip_atomic_fetch_add(&bar[0], 1u, __ATOMIC_ACQ_REL, __HIP_MEMORY_SCOPE_AGENT);
    if (old == NB - 1u) {
      __hip_atomic_store(&bar[0], 0u, __ATOMIC_RELAXED, __HIP_MEMORY_SCOPE_AGENT);
      __hip_atomic_fetch_add(&bar[1], 1u, __ATOMIC_RELEASE, __HIP_MEMORY_SCOPE_AGENT);
    } else {
      while (__hip_atomic_load(&bar[1], __ATOMIC_ACQUIRE, __HIP_MEMORY_SCOPE_AGENT) < target) {
        __builtin_amdgcn_s_sleep(2);
      }
    }
  }
  __syncthreads();
  __threadfence();  // acquire: invalidate L1/L2 so cross-XCD v writes are visible
}

// ---------------- precompute: WT[:, 0:1024] = W1 @ W2 (row stride 1280) ----------------
__global__ __launch_bounds__(256) void k_gemm_wt(const float* __restrict__ A,
                                                 const float* __restrict__ B,
                                                 float* __restrict__ WT) {
  __shared__ float As[32][68];  // As[jj][r] = A[by*64+r][j0+jj]
  __shared__ float Bs[32][68];  // Bs[jj][c] = B[j0+jj][bx*64+c]
  const int tid = threadIdx.x;
  const int tx = tid & 15, ty = tid >> 4;
  const int bx = blockIdx.x, by = blockIdx.y;
  float acc[4][4] = {};
  for (int j0 = 0; j0 < WDIM; j0 += 32) {
    for (int l = tid; l < 64 * 32; l += 256) {
      int r = l >> 5, c = l & 31;
      As[c][r] = A[(by * 64 + r) * WDIM + j0 + c];
    }
    for (int l = tid; l < 32 * 64; l += 256) {
      int r = l >> 6, c = l & 63;
      Bs[r][c] = B[(j0 + r) * WDIM + bx * 64 + c];
    }
    __syncthreads();
#pragma unroll
    for (int kk = 0; kk < 32; ++kk) {
      float a[4], bb[4];
      *(float4*)a  = *(const float4*)&As[kk][ty * 4];
      *(float4*)bb = *(const float4*)&Bs[kk][tx * 4];
#pragma unroll
      for (int i = 0; i < 4; ++i)
#pragma unroll
        for (int j = 0; j < 4; ++j) acc[i][j] += a[i] * bb[j];
    }
    __syncthreads();
  }
#pragma unroll
  for (int i = 0; i < 4; ++i)
#pragma unroll
    for (int j = 0; j < 4; ++j)
      WT[(size_t)(by * 64 + ty * 4 + i) * WSTRIDE + bx * 64 + tx * 4 + j] = acc[i][j];
}

// ---------------- precompute: WT[n][1024+k] = W1[n][k] (k<256); reset barrier ----------------
__global__ __launch_bounds__(256) void k_copy(const float* __restrict__ W1,
                                              float* __restrict__ WT, unsigned* bar) {
  int n = blockIdx.x;
  int k = threadIdx.x;
  WT[(size_t)n * WSTRIDE + WDIM + k] = W1[n * WDIM + k];
  if (n == 0 && k == 0) { bar[0] = 0u; bar[1] = 0u; }
}

// ---------------- precompute: b1c[n] = b1[n] + b2@W1^T ; c0[n] = b1[n] + s0@W1^T ----------------
__global__ __launch_bounds__(256) void k_bias(const float* __restrict__ W1,
                                              const float* __restrict__ b1,
                                              const float* __restrict__ b2,
                                              const float* __restrict__ s0,
                                              float* __restrict__ b1c,
                                              float* __restrict__ c0) {
  int wave = threadIdx.x >> 6;
  int lane = threadIdx.x & 63;
  int n = blockIdx.x * 4 + wave;   // 1024 waves total
  const float* row = W1 + (size_t)n * WDIM;
  float a1 = 0.f, a2 = 0.f;
  for (int k = lane; k < WDIM; k += 64) {
    float w = row[k];
    a1 += b2[k] * w;
    a2 += s0[k] * w;
  }
#pragma unroll
  for (int off = 32; off; off >>= 1) {
    a1 += __shfl_down(a1, off, 64);
    a2 += __shfl_down(a2, off, 64);
  }
  if (lane == 0) { b1c[n] = b1[n] + a1; c0[n] = b1[n] + a2; }
}

// ---------------- main persistent recurrent kernel ----------------
// grid: 256 blocks x 256 threads. block = (batch group g: 16 rows) x (n-tile nt: 16 cols)
// nt = blockIdx & 63 so the 4 batch groups of an n-tile share an XCD (blk mod 8 equal)
// -> each XCD's 8 WT n-slices (640 KB) stay L2-resident across all 2048 steps.
__global__ __launch_bounds__(256) void k_main(
    const float* __restrict__ x, const float* __restrict__ WT,
    const float* __restrict__ b1c, const float* __restrict__ c0,
    const float* __restrict__ W2, const float* __restrict__ b2,
    const float* __restrict__ bend, const float* __restrict__ inner,
    const float* __restrict__ outer,
    float* vA, float* vB, float* __restrict__ out, unsigned* bar) {
  __shared__ float vs[16 * 1024];  // staged v quarter, float4-XOR-swizzled (64 KB)
  const int tid = threadIdx.x;
  const int tx = tid & 15, ty = tid >> 4;
  const int nt = blockIdx.x & 63, g = blockIdx.x >> 6;
  const int b = g * 16 + ty;
  const int n = nt * 16 + tx;

  // zero initial state v_{-1} (grid exactly covers 64*1024 elements)
  vA[blockIdx.x * 256 + tid] = 0.0f;

  const float bo  = bend[n] * outer[n];
  const float inw = inner[n];
  const float* wrow = WT + (size_t)n * WSTRIDE;
  float4* vs4 = (float4*)vs;
  const int sw = (ty & 3) << 1;  // float4-granular XOR swizzle: spreads 4 wave rows over banks

  unsigned gent = 0;
  float* vin = vA;
  float* vout = vB;
  gbar(bar, ++gent);  // zeros visible everywhere

  for (int t = 0; t < SEQ_N; ++t) {
    // stage this block's v quarter (16 x 1024) into LDS, swizzled
    const float4* vsrc = (const float4*)(vin + (size_t)g * 16 * WDIM);
#pragma unroll
    for (int j = 0; j < 16; ++j) {
      int i = j * 256 + tid;         // float4 index 0..4095
      int r = i >> 8;                // row 0..15
      int c4 = i & 255;              // float4 col
      vs4[r * 256 + (c4 ^ ((r & 3) << 1))] = vsrc[i];
    }
    __syncthreads();

    float acc0 = 0.f, acc1 = 0.f, acc2 = 0.f, acc3 = 0.f;
    const float4* vrow4 = vs4 + ty * 256;
    const float4* wr4 = (const float4*)wrow;
#pragma unroll 8
    for (int k4 = 0; k4 < 256; ++k4) {
      float4 w = wr4[k4];
      float4 v = vrow4[k4 ^ sw];
      acc0 += w.x * v.x; acc1 += w.y * v.y; acc2 += w.z * v.z; acc3 += w.w * v.w;
    }
    // input injection: + x[t,b,:] @ W1[:, :256]^T  (WT cols 1024..1279)
    const float4* xr  = (const float4*)(x + ((size_t)t * BATCH + b) * KX);
    const float4* wxr = (const float4*)(wrow + WDIM);
#pragma unroll 8
    for (int k4 = 0; k4 < KX / 4; ++k4) {
      float4 w = wxr[k4];
      float4 v = xr[k4];
      acc0 += w.x * v.x; acc1 += w.y * v.y; acc2 += w.z * v.z; acc3 += w.w * v.w;
    }
    float u = ((acc0 + acc1) + (acc2 + acc3)) + (t == 0 ? c0[n] : b1c[n]);
    float gv = u + bo * sinf(u * inw);
    vout[(size_t)b * WDIM + n] = gv;

    gbar(bar, ++gent);
    float* tmp = vin; vin = vout; vout = tmp;
  }

  // final: stream = v_{2047} @ W2^T + b2
  {
    const float4* vsrc = (const float4*)(vin + (size_t)g * 16 * WDIM);
#pragma unroll
    for (int j = 0; j < 16; ++j) {
      int i = j * 256 + tid;
      int r = i >> 8;
      int c4 = i & 255;
      vs4[r * 256 + (c4 ^ ((r & 3) << 1))] = vsrc[i];
    }
    __syncthreads();
    float acc0 = 0.f, acc1 = 0.f, acc2 = 0.f, acc3 = 0.f;
    const float4* vrow4 = vs4 + ty * 256;
    const float4* w2r = (const float4*)(W2 + (size_t)n * WDIM);
#pragma unroll 8
    for (int k4 = 0; k4 < 256; ++k4) {
      float4 w = w2r[k4];
      float4 v = vrow4[k4 ^ sw];
      acc0 += w.x * v.x; acc1 += w.y * v.y; acc2 += w.z * v.z; acc3 += w.w * v.w;
    }
    float s = ((acc0 + acc1) + (acc2 + acc3)) + b2[n];
    out[4096 + (size_t)b * WDIM + n] = s;   // `final` (64x1024)
    if (n < 64) out[(size_t)b * 64 + n] = s; // `outputs` = final[:, :64]
  }
}

extern "C" void kernel_launch(void* const* d_in, const int* in_sizes, int n_in,
                              void* d_out, int out_size, void* d_ws, size_t ws_size,
                              hipStream_t stream) {
  const float* x    = (const float*)d_in[0];  // (2048, 64, 256)
  const float* s0   = (const float*)d_in[1];  // (1024,)
  const float* W1   = (const float*)d_in[2];  // (1024, 1024)
  const float* b1   = (const float*)d_in[3];
  const float* W2   = (const float*)d_in[4];
  const float* b2   = (const float*)d_in[5];
  const float* bend = (const float*)d_in[6];
  const float* inner= (const float*)d_in[7];
  const float* outer= (const float*)d_in[8];
  float* ws = (float*)d_ws;

  float* WT  = ws;
  float* b1c = ws + 1310720;
  float* c0  = ws + 1311744;
  float* vA  = ws + 1312768;
  float* vB  = ws + 1378304;
  unsigned* bar = (unsigned*)(ws + 1443840);
  float* out = (float*)d_out;

  k_gemm_wt<<<dim3(16, 16), 256, 0, stream>>>(W1, W2, WT);
  k_copy<<<1024, 256, 0, stream>>>(W1, WT, bar);
  k_bias<<<256, 256, 0, stream>>>(W1, b1, b2, s0, b1c, c0);

  void* args[] = { (void*)&x, (void*)&WT, (void*)&b1c, (void*)&c0, (void*)&W2,
                   (void*)&b2, (void*)&bend, (void*)&inner, (void*)&outer,
                   (void*)&vA, (void*)&vB, (void*)&out, (void*)&bar };
  hipLaunchCooperativeKernel((void*)k_main, dim3(NB), dim3(256), args, 0, stream);
}

// Round 4
// 68495.752 us; speedup vs baseline: 2.2600x; 2.2600x over previous
//
#include <hip/hip_runtime.h>
#include <math.h>

// ResRnn on MI355X — round 4: fp64 recurrence (chaos-proof numerics).
// u_t = v_{t-1} @ Wc^T(row-major Wcd[n][k]) + bias + x_t @ W1p^T ; v_t = u + bo*sin(u*inw)
// Wcd = W1@W2 in fp64. State v, biases, all accumulation: fp64.
// Weights stream from L2 every step (no register residency); per-step barrier uses
// RELEASE-only fences (no L2 invalidate) so weights stay L2-resident; cross-XCD v
// exchange via agent-scope relaxed atomics (coherent at L3).

#define WDIM 1024
#define SEQ_N 2048
#define NB 256

// ---- workspace layout (double offsets) ----
// Wcd [1024][1024] @ 0 ; b1c @ 1048576 ; c0 @ 1049600 ; vA @ 1050624 ; vB @ 1116160
// bar (unsigned[288]) @ double-offset 1181696

__device__ __forceinline__ double gload(const double* p) {
  unsigned long long v = __hip_atomic_load((const unsigned long long*)p,
                                           __ATOMIC_RELAXED, __HIP_MEMORY_SCOPE_AGENT);
  return __builtin_bit_cast(double, v);
}
__device__ __forceinline__ void gstore(double* p, double d) {
  __hip_atomic_store((unsigned long long*)p, __builtin_bit_cast(unsigned long long, d),
                     __ATOMIC_RELAXED, __HIP_MEMORY_SCOPE_AGENT);
}

// ---- grid barrier: 16-leaf tree, relaxed atomics + release-only fence (no inv) ----
__device__ __forceinline__ void gbar(unsigned* bar, unsigned target, int leaf) {
  __syncthreads();
  if (threadIdx.x == 0) {
    __builtin_amdgcn_fence(__ATOMIC_RELEASE, "agent");  // writeback, no invalidate
    unsigned old = __hip_atomic_fetch_add(&bar[32 + leaf * 16], 1u, __ATOMIC_RELAXED,
                                          __HIP_MEMORY_SCOPE_AGENT);
    if (old + 1u == target * 16u) {
      unsigned r = __hip_atomic_fetch_add(&bar[16], 1u, __ATOMIC_RELAXED,
                                          __HIP_MEMORY_SCOPE_AGENT);
      if (r + 1u == target * 16u)
        __hip_atomic_store(&bar[0], target, __ATOMIC_RELAXED, __HIP_MEMORY_SCOPE_AGENT);
    }
    while (__hip_atomic_load(&bar[0], __ATOMIC_RELAXED, __HIP_MEMORY_SCOPE_AGENT) < target)
      __builtin_amdgcn_s_sleep(2);
  }
  __syncthreads();
}

// ---- precompute: Wcd[n][k] = sum_j W1[n][j]*W2[j][k], fp64 accumulate/store ----
__global__ __launch_bounds__(256) void k_gemm_wt(const float* __restrict__ A,
                                                 const float* __restrict__ B,
                                                 double* __restrict__ Wcd) {
  __shared__ float As[32][68];
  __shared__ float Bs[32][68];
  const int tid = threadIdx.x;
  const int tx = tid & 15, ty = tid >> 4;
  const int bx = blockIdx.x, by = blockIdx.y;
  double acc[4][4] = {};
  for (int j0 = 0; j0 < WDIM; j0 += 32) {
    for (int l = tid; l < 64 * 32; l += 256) {
      int r = l >> 5, c = l & 31;
      As[c][r] = A[(by * 64 + r) * WDIM + j0 + c];
    }
    for (int l = tid; l < 32 * 64; l += 256) {
      int r = l >> 6, c = l & 63;
      Bs[r][c] = B[(j0 + r) * WDIM + bx * 64 + c];
    }
    __syncthreads();
#pragma unroll 8
    for (int kk = 0; kk < 32; ++kk) {
      float a[4], bb[4];
      *(float4*)a  = *(const float4*)&As[kk][ty * 4];
      *(float4*)bb = *(const float4*)&Bs[kk][tx * 4];
#pragma unroll
      for (int i = 0; i < 4; ++i)
#pragma unroll
        for (int j = 0; j < 4; ++j) acc[i][j] += (double)a[i] * (double)bb[j];
    }
    __syncthreads();
  }
#pragma unroll
  for (int i = 0; i < 4; ++i)
#pragma unroll
    for (int j = 0; j < 4; ++j)
      Wcd[(size_t)(by * 64 + ty * 4 + i) * WDIM + bx * 64 + tx * 4 + j] = acc[i][j];
}

// ---- precompute: fp64 biases; zero barrier ----
__global__ __launch_bounds__(256) void k_bias(const float* __restrict__ W1,
                                              const float* __restrict__ b1,
                                              const float* __restrict__ b2,
                                              const float* __restrict__ s0,
                                              double* __restrict__ b1c,
                                              double* __restrict__ c0, unsigned* bar) {
  if (blockIdx.x < 2) {
    int i = blockIdx.x * 256 + threadIdx.x;
    if (i < 288) bar[i] = 0u;
  }
  int wave = threadIdx.x >> 6;
  int lane = threadIdx.x & 63;
  int n = blockIdx.x * 4 + wave;
  const float* row = W1 + (size_t)n * WDIM;
  double a1 = 0.0, a2 = 0.0;
  for (int k = lane; k < WDIM; k += 64) {
    double w = (double)row[k];
    a1 += (double)b2[k] * w;
    a2 += (double)s0[k] * w;
  }
#pragma unroll
  for (int off = 32; off; off >>= 1) {
    a1 += __shfl_down(a1, off, 64);
    a2 += __shfl_down(a2, off, 64);
  }
  if (lane == 0) { b1c[n] = (double)b1[n] + a1; c0[n] = (double)b1[n] + a2; }
}

// ---- main persistent recurrent kernel (fp64) ----
// block (g=blk>>6, nt=blk&63): 16 b-rows x 16 n-cols. thread: ks=tid&15, bg=(tid>>4)&3,
// ng=tid>>6. Per thread: 4b x 4n outputs' partial over k-slice {i*16+ks} (double2 units).
__global__ __launch_bounds__(256, 1) void k_main(
    const float* __restrict__ x, const double* __restrict__ Wcd,
    const float* __restrict__ W1, const double* __restrict__ b1c,
    const double* __restrict__ c0, const float* __restrict__ W2,
    const float* __restrict__ b2, const float* __restrict__ bend,
    const float* __restrict__ inner, const float* __restrict__ outer,
    double* vA, double* vB, float* __restrict__ out, unsigned* bar) {
  __shared__ double2 smd2[4096];  // 64 KB: half v-tile [16][256]d2 (XOR r&7) / reduce buf
  const int tid = threadIdx.x;
  const int ks = tid & 15;
  const int bg = (tid >> 4) & 3;
  const int ng = tid >> 6;
  const int nt = blockIdx.x & 63, g = blockIdx.x >> 6;
  const int leaf = blockIdx.x >> 4;

  // zero v_{-1} (doubles; grid covers 65536 exactly); flushed by first gbar's release
  vA[blockIdx.x * 256 + tid] = 0.0;

  // weight row base pointers (L2-resident across the whole loop)
  const double* wrow[4];
  const float* w1row[4];
  const float* w2row[4];
#pragma unroll
  for (int jn = 0; jn < 4; ++jn) {
    int n = nt * 16 + ng * 4 + jn;
    wrow[jn] = Wcd + (size_t)n * WDIM;
    w1row[jn] = W1 + (size_t)n * WDIM;
    w2row[jn] = W2 + (size_t)n * WDIM;
  }

  // reducer-role constants (thread o = tid owns output (b_red, n_red))
  const int n_red = nt * 16 + (tid & 15);
  const int b_red = g * 16 + (tid >> 4);
  const double bo   = (double)bend[n_red] * (double)outer[n_red];
  const double inw  = (double)inner[n_red];
  const double b1cr = b1c[n_red];
  const double c0r  = c0[n_red];

  unsigned gent = 0;
  double* vin = vA;
  double* vout = vB;
  gbar(bar, ++gent, leaf);

  for (int t = 0; t < SEQ_N; ++t) {
    double accx[4][4], accy[4][4];
#pragma unroll
    for (int ib = 0; ib < 4; ++ib)
#pragma unroll
      for (int jn = 0; jn < 4; ++jn) { accx[ib][jn] = 0.0; accy[ib][jn] = 0.0; }

#pragma unroll 1
    for (int half = 0; half < 2; ++half) {
      // stage half v-tile: 16 rows x 256 double2, agent-coherent 8B loads
#pragma unroll
      for (int j = 0; j < 16; ++j) {
        int idx = j * 256 + tid;
        int r = idx >> 8, c2 = idx & 255;
        const double* src = vin + (size_t)(g * 16 + r) * WDIM + half * 512 + c2 * 2;
        double d0 = gload(src), d1 = gload(src + 1);
        smd2[r * 256 + (c2 ^ (r & 7))] = make_double2(d0, d1);
      }
      __syncthreads();

#pragma unroll 4
      for (int i = 0; i < 16; ++i) {
        int c2 = i * 16 + ks;
        double2 v0 = smd2[(bg * 4 + 0) * 256 + (c2 ^ ((bg * 4 + 0) & 7))];
        double2 v1 = smd2[(bg * 4 + 1) * 256 + (c2 ^ ((bg * 4 + 1) & 7))];
        double2 v2 = smd2[(bg * 4 + 2) * 256 + (c2 ^ ((bg * 4 + 2) & 7))];
        double2 v3 = smd2[(bg * 4 + 3) * 256 + (c2 ^ ((bg * 4 + 3) & 7))];
#pragma unroll
        for (int jn = 0; jn < 4; ++jn) {
          double2 w = *(const double2*)(wrow[jn] + half * 512 + c2 * 2);
          accx[0][jn] += v0.x * w.x; accy[0][jn] += v0.y * w.y;
          accx[1][jn] += v1.x * w.x; accy[1][jn] += v1.y * w.y;
          accx[2][jn] += v2.x * w.x; accy[2][jn] += v2.y * w.y;
          accx[3][jn] += v3.x * w.x; accy[3][jn] += v3.y * w.y;
        }
      }
      __syncthreads();
    }

    // x injection: x[t, b, 0:256] @ W1[:, 0:256]^T (fp32 inputs, fp64 math)
    {
      const float2* xr0 = (const float2*)(x + ((size_t)t * 64 + g * 16 + bg * 4 + 0) * 256);
      const float2* xr1 = (const float2*)(x + ((size_t)t * 64 + g * 16 + bg * 4 + 1) * 256);
      const float2* xr2 = (const float2*)(x + ((size_t)t * 64 + g * 16 + bg * 4 + 2) * 256);
      const float2* xr3 = (const float2*)(x + ((size_t)t * 64 + g * 16 + bg * 4 + 3) * 256);
#pragma unroll 4
      for (int i = 0; i < 8; ++i) {
        int c2 = i * 16 + ks;
        float2 xv0 = xr0[c2], xv1 = xr1[c2], xv2 = xr2[c2], xv3 = xr3[c2];
#pragma unroll
        for (int jn = 0; jn < 4; ++jn) {
          float2 wf = *(const float2*)(w1row[jn] + c2 * 2);
          double wx = (double)wf.x, wy = (double)wf.y;
          accx[0][jn] += (double)xv0.x * wx; accy[0][jn] += (double)xv0.y * wy;
          accx[1][jn] += (double)xv1.x * wx; accy[1][jn] += (double)xv1.y * wy;
          accx[2][jn] += (double)xv2.x * wx; accy[2][jn] += (double)xv2.y * wy;
          accx[3][jn] += (double)xv3.x * wx; accy[3][jn] += (double)xv3.y * wy;
        }
      }
    }

    // stage partials: slot = o*16 + (ks ^ (o&7)), o = output index
#pragma unroll
    for (int ib = 0; ib < 4; ++ib)
#pragma unroll
      for (int jn = 0; jn < 4; ++jn) {
        int o = (bg * 4 + ib) * 16 + ng * 4 + jn;
        smd2[o * 16 + (ks ^ (o & 7))] = make_double2(accx[ib][jn], accy[ib][jn]);
      }
    __syncthreads();

    // reduce: thread o sums 16 slices in ks-ascending order (fp64)
    {
      double s = 0.0;
      const int oc = tid & 7;
#pragma unroll
      for (int slc = 0; slc < 16; ++slc) {
        double2 p = smd2[tid * 16 + (slc ^ oc)];
        s += p.x + p.y;
      }
      double u = s + (t == 0 ? c0r : b1cr);
      double gv = u + bo * sin(u * inw);
      gstore(&vout[(size_t)b_red * WDIM + n_red], gv);
    }

    gbar(bar, ++gent, leaf);
    double* tmp = vin; vin = vout; vout = tmp;
  }

  // ---- epilogue: stream = v_2047 @ W2^T + b2 (fp64), cast to fp32 out ----
  {
    double accx2[4][4], accy2[4][4];
#pragma unroll
    for (int ib = 0; ib < 4; ++ib)
#pragma unroll
      for (int jn = 0; jn < 4; ++jn) { accx2[ib][jn] = 0.0; accy2[ib][jn] = 0.0; }

#pragma unroll 1
    for (int half = 0; half < 2; ++half) {
#pragma unroll
      for (int j = 0; j < 16; ++j) {
        int idx = j * 256 + tid;
        int r = idx >> 8, c2 = idx & 255;
        const double* src = vin + (size_t)(g * 16 + r) * WDIM + half * 512 + c2 * 2;
        double d0 = gload(src), d1 = gload(src + 1);
        smd2[r * 256 + (c2 ^ (r & 7))] = make_double2(d0, d1);
      }
      __syncthreads();
#pragma unroll 4
      for (int i = 0; i < 16; ++i) {
        int c2 = i * 16 + ks;
        double2 v0 = smd2[(bg * 4 + 0) * 256 + (c2 ^ ((bg * 4 + 0) & 7))];
        double2 v1 = smd2[(bg * 4 + 1) * 256 + (c2 ^ ((bg * 4 + 1) & 7))];
        double2 v2 = smd2[(bg * 4 + 2) * 256 + (c2 ^ ((bg * 4 + 2) & 7))];
        double2 v3 = smd2[(bg * 4 + 3) * 256 + (c2 ^ ((bg * 4 + 3) & 7))];
#pragma unroll
        for (int jn = 0; jn < 4; ++jn) {
          float2 wf = *(const float2*)(w2row[jn] + half * 512 + c2 * 2);
          double wx = (double)wf.x, wy = (double)wf.y;
          accx2[0][jn] += v0.x * wx; accy2[0][jn] += v0.y * wy;
          accx2[1][jn] += v1.x * wx; accy2[1][jn] += v1.y * wy;
          accx2[2][jn] += v2.x * wx; accy2[2][jn] += v2.y * wy;
          accx2[3][jn] += v3.x * wx; accy2[3][jn] += v3.y * wy;
        }
      }
      __syncthreads();
    }
#pragma unroll
    for (int ib = 0; ib < 4; ++ib)
#pragma unroll
      for (int jn = 0; jn < 4; ++jn) {
        int o = (bg * 4 + ib) * 16 + ng * 4 + jn;
        smd2[o * 16 + (ks ^ (o & 7))] = make_double2(accx2[ib][jn], accy2[ib][jn]);
      }
    __syncthreads();
    {
      double s = 0.0;
      const int oc = tid & 7;
#pragma unroll
      for (int slc = 0; slc < 16; ++slc) {
        double2 p = smd2[tid * 16 + (slc ^ oc)];
        s += p.x + p.y;
      }
      double sv = s + (double)b2[n_red];
      out[4096 + (size_t)b_red * WDIM + n_red] = (float)sv;
      if (n_red < 64) out[(size_t)b_red * 64 + n_red] = (float)sv;
    }
  }
}

extern "C" void kernel_launch(void* const* d_in, const int* in_sizes, int n_in,
                              void* d_out, int out_size, void* d_ws, size_t ws_size,
                              hipStream_t stream) {
  const float* x    = (const float*)d_in[0];
  const float* s0   = (const float*)d_in[1];
  const float* W1   = (const float*)d_in[2];
  const float* b1   = (const float*)d_in[3];
  const float* W2   = (const float*)d_in[4];
  const float* b2   = (const float*)d_in[5];
  const float* bend = (const float*)d_in[6];
  const float* inner= (const float*)d_in[7];
  const float* outer= (const float*)d_in[8];
  double* ws = (double*)d_ws;

  double* Wcd = ws;
  double* b1c = ws + 1048576;
  double* c0  = ws + 1049600;
  double* vA  = ws + 1050624;
  double* vB  = ws + 1116160;
  unsigned* bar = (unsigned*)(ws + 1181696);
  float* out = (float*)d_out;

  k_gemm_wt<<<dim3(16, 16), 256, 0, stream>>>(W1, W2, Wcd);
  k_bias<<<256, 256, 0, stream>>>(W1, b1, b2, s0, b1c, c0, bar);

  int maxB = 0;
  hipError_t qe = hipOccupancyMaxActiveBlocksPerMultiprocessor(&maxB, k_main, 256, 0);
  bool coop = (qe == hipSuccess) && (maxB >= 2);
  if (coop) {
    void* args[] = { (void*)&x, (void*)&Wcd, (void*)&W1, (void*)&b1c, (void*)&c0,
                     (void*)&W2, (void*)&b2, (void*)&bend, (void*)&inner, (void*)&outer,
                     (void*)&vA, (void*)&vB, (void*)&out, (void*)&bar };
    hipLaunchCooperativeKernel((void*)k_main, dim3(NB), dim3(256), args, 0, stream);
  } else {
    k_main<<<dim3(NB), dim3(256), 0, stream>>>(x, Wcd, W1, b1c, c0, W2, b2, bend, inner,
                                               outer, vA, vB, out, bar);
  }
}